// Round 2
// baseline (441.916 us; speedup 1.0000x reference)
//
#include <hip/hip_runtime.h>
#include <math.h>

#define DDIM 256
#define NWAVES 4
#define NEG_SENT -1.0e30f   // finite sentinel: avoids (-inf) - (-inf) = NaN in merges

// Kernel A: offsets[i] = lower_bound(seg, i) for i in [0, S]; seg is sorted.
__global__ void seg_offsets_kernel(const int* __restrict__ seg, int E, int S,
                                   int* __restrict__ offs) {
    int i = blockIdx.x * blockDim.x + threadIdx.x;
    if (i > S) return;
    int lo = 0, hi = E;
    while (lo < hi) {
        int mid = (lo + hi) >> 1;
        if (seg[mid] < i) lo = mid + 1; else hi = mid;
    }
    offs[i] = lo;
}

// Kernel B: per-node logits, one wave per row (64 lanes x float4 = full row).
// Streams z once (205 MB) -> ~35 us; also warms L3 for the gather kernel.
__global__ __launch_bounds__(256)
void node_logits_kernel(const float4* __restrict__ z4,
                        const float* __restrict__ attn_w,
                        const float* __restrict__ attn_b,
                        float* __restrict__ logits, int N) {
    const int wave = threadIdx.x >> 6;
    const int lane = threadIdx.x & 63;
    const int row  = blockIdx.x * NWAVES + wave;
    if (row >= N) return;
    const float  b  = attn_b[0];
    const float4 wv = ((const float4*)attn_w)[lane];
    const float4 v  = z4[(long)row * (DDIM / 4) + lane];
    float part = v.x * wv.x + v.y * wv.y + v.z * wv.z + v.w * wv.w;
    #pragma unroll
    for (int sh = 32; sh >= 1; sh >>= 1) part += __shfl_xor(part, sh);
    if (lane == 0) logits[row] = part + b;
}

// Kernel C: one block per segment. Pass 1 computes EXACT (M, den) from the
// precomputed logits (4 B/edge, cache-resident). Pass 2 is a pure gather+fma
// accumulate with no cross-lane ops and no online rescale -> pipelineable.
__global__ __launch_bounds__(256)
void segpool2_kernel(const float4* __restrict__ z4,
                     const float* __restrict__ logits,
                     const int* __restrict__ idx,
                     const int* __restrict__ offs,
                     float* __restrict__ out) {
    const int s     = blockIdx.x;
    const int start = offs[s];
    const int end   = offs[s + 1];
    const int tid   = threadIdx.x;

    if (end <= start) {                 // empty segment -> zeros
        out[(long)s * DDIM + tid] = 0.0f;
        return;
    }

    const int wave = tid >> 6;
    const int lane = tid & 63;

    __shared__ float red_m[NWAVES], red_l[NWAVES];
    __shared__ float s_M, s_invden;
    __shared__ float lds_acc[NWAVES][DDIM];

    // ---- Pass 1: exact segment max + denominator over logits ----
    float m = NEG_SENT, l = 0.0f;
    for (int e = start + tid; e < end; e += 256) {
        const float lg = logits[idx[e]];
        const float nm = fmaxf(m, lg);
        l = l * __expf(m - nm) + __expf(lg - nm);
        m = nm;
    }
    #pragma unroll
    for (int sh = 32; sh >= 1; sh >>= 1) {
        const float om = __shfl_xor(m, sh);
        const float ol = __shfl_xor(l, sh);
        const float nm = fmaxf(m, om);
        l = l * __expf(m - nm) + ol * __expf(om - nm);
        m = nm;
    }
    if (lane == 0) { red_m[wave] = m; red_l[wave] = l; }
    __syncthreads();
    if (tid == 0) {
        float M = fmaxf(fmaxf(red_m[0], red_m[1]), fmaxf(red_m[2], red_m[3]));
        float den = 0.0f;
        #pragma unroll
        for (int w = 0; w < NWAVES; ++w) den += red_l[w] * __expf(red_m[w] - M);
        s_M = M;
        s_invden = 1.0f / den;
    }
    __syncthreads();
    const float M = s_M;
    const float invden = s_invden;

    // ---- Pass 2: gather + weighted accumulate (only dep: acc fma) ----
    float4 acc = make_float4(0.f, 0.f, 0.f, 0.f);
    #pragma unroll 4
    for (int e = start + wave; e < end; e += NWAVES) {
        const int   row = idx[e];
        const float p   = __expf(logits[row] - M);
        const float4 v  = z4[(long)row * (DDIM / 4) + lane];
        acc.x += p * v.x;
        acc.y += p * v.y;
        acc.z += p * v.z;
        acc.w += p * v.w;
    }

    lds_acc[wave][4 * lane + 0] = acc.x;
    lds_acc[wave][4 * lane + 1] = acc.y;
    lds_acc[wave][4 * lane + 2] = acc.z;
    lds_acc[wave][4 * lane + 3] = acc.w;
    __syncthreads();

    const float o = lds_acc[0][tid] + lds_acc[1][tid] +
                    lds_acc[2][tid] + lds_acc[3][tid];
    out[(long)s * DDIM + tid] = o * invden;
}

// ---- Fallback (R1 fused online-softmax kernel) if ws is too small ----
__global__ __launch_bounds__(256)
void segpool_fused_kernel(const float* __restrict__ z,
                          const float* __restrict__ attn_w,
                          const float* __restrict__ attn_b,
                          const int* __restrict__ idx,
                          const int* __restrict__ offs,
                          float* __restrict__ out) {
    const int s     = blockIdx.x;
    const int start = offs[s];
    const int end   = offs[s + 1];
    const int tid   = threadIdx.x;
    if (end <= start) { out[(long)s * DDIM + tid] = 0.0f; return; }
    const int wave = tid >> 6;
    const int lane = tid & 63;
    const float4 wv = ((const float4*)attn_w)[lane];
    const float  b  = attn_b[0];
    const float4* __restrict__ z4 = (const float4*)z;
    float  m = NEG_SENT, l = 0.0f;
    float4 acc = make_float4(0.f, 0.f, 0.f, 0.f);
    for (int e = start + wave; e < end; e += NWAVES) {
        const int   row = idx[e];
        const float4 v  = z4[(long)row * (DDIM / 4) + lane];
        float part = v.x * wv.x + v.y * wv.y + v.z * wv.z + v.w * wv.w;
        #pragma unroll
        for (int sh = 32; sh >= 1; sh >>= 1) part += __shfl_xor(part, sh);
        const float logit = part + b;
        const float nm    = fmaxf(m, logit);
        const float alpha = __expf(m - nm);
        const float p     = __expf(logit - nm);
        l = l * alpha + p;
        acc.x = acc.x * alpha + p * v.x;
        acc.y = acc.y * alpha + p * v.y;
        acc.z = acc.z * alpha + p * v.z;
        acc.w = acc.w * alpha + p * v.w;
        m = nm;
    }
    __shared__ float lds_m[NWAVES], lds_l[NWAVES];
    __shared__ float lds_acc[NWAVES][DDIM];
    if (lane == 0) { lds_m[wave] = m; lds_l[wave] = l; }
    __syncthreads();
    const float M = fmaxf(fmaxf(lds_m[0], lds_m[1]), fmaxf(lds_m[2], lds_m[3]));
    float den = 0.0f;
    #pragma unroll
    for (int w = 0; w < NWAVES; ++w) den += __expf(lds_m[w] - M) * lds_l[w];
    const float scale = __expf(m - M);
    lds_acc[wave][4 * lane + 0] = acc.x * scale;
    lds_acc[wave][4 * lane + 1] = acc.y * scale;
    lds_acc[wave][4 * lane + 2] = acc.z * scale;
    lds_acc[wave][4 * lane + 3] = acc.w * scale;
    __syncthreads();
    const float o = lds_acc[0][tid] + lds_acc[1][tid] +
                    lds_acc[2][tid] + lds_acc[3][tid];
    out[(long)s * DDIM + tid] = o / den;
}

extern "C" void kernel_launch(void* const* d_in, const int* in_sizes, int n_in,
                              void* d_out, int out_size, void* d_ws, size_t ws_size,
                              hipStream_t stream) {
    const float* z      = (const float*)d_in[0];
    const float* attn_w = (const float*)d_in[1];
    const float* attn_b = (const float*)d_in[2];
    const int*   idx    = (const int*)d_in[3];
    const int*   seg    = (const int*)d_in[4];
    float*       out    = (float*)d_out;

    const int E = in_sizes[3];
    const int S = out_size / DDIM;
    const int N = in_sizes[0] / DDIM;

    const int threads = 256;
    const int gridA = (S + 1 + threads - 1) / threads;

    int* offs = (int*)d_ws;
    const size_t offs_bytes = (((size_t)(S + 1) * sizeof(int)) + 255) & ~(size_t)255;
    const size_t need = offs_bytes + (size_t)N * sizeof(float);

    seg_offsets_kernel<<<gridA, threads, 0, stream>>>(seg, E, S, offs);

    if (ws_size >= need) {
        float* logits = (float*)((char*)d_ws + offs_bytes);
        const int gridB = (N + NWAVES - 1) / NWAVES;
        node_logits_kernel<<<gridB, threads, 0, stream>>>(
            (const float4*)z, attn_w, attn_b, logits, N);
        segpool2_kernel<<<S, threads, 0, stream>>>(
            (const float4*)z, logits, idx, offs, out);
    } else {
        segpool_fused_kernel<<<S, threads, 0, stream>>>(
            z, attn_w, attn_b, idx, offs, out);
    }
}

// Round 3
// 376.438 us; speedup vs baseline: 1.1739x; 1.1739x over previous
//
#include <hip/hip_runtime.h>
#include <hip/hip_fp16.h>
#include <math.h>

#define DDIM 256
#define NWAVES 4
#define NEG_SENT -1.0e30f

// ---------- Kernel A: offsets[i] = lower_bound(seg, i), seg sorted ----------
__global__ void seg_offsets_kernel(const int* __restrict__ seg, int E, int S,
                                   int* __restrict__ offs) {
    int i = blockIdx.x * blockDim.x + threadIdx.x;
    if (i > S) return;
    int lo = 0, hi = E;
    while (lo < hi) {
        int mid = (lo + hi) >> 1;
        if (seg[mid] < i) lo = mid + 1; else hi = mid;
    }
    offs[i] = lo;
}

// ---------- Kernel B: per-node p = exp(z.w + b), plus f16 copy of z ----------
// One wave per row: lane l handles dims [4l, 4l+4). Streams z once.
__global__ __launch_bounds__(256)
void prep_kernel(const float4* __restrict__ z4,
                 const float* __restrict__ attn_w,
                 const float* __restrict__ attn_b,
                 uint2* __restrict__ z16,      // N x 64 uint2 (4 halves each)
                 float* __restrict__ pvec, int N) {
    const int wave = threadIdx.x >> 6;
    const int lane = threadIdx.x & 63;
    const int row  = blockIdx.x * NWAVES + wave;
    if (row >= N) return;
    const float4 v = z4[(long)row * 64 + lane];
    __half2 h0 = __floats2half2_rn(v.x, v.y);
    __half2 h1 = __floats2half2_rn(v.z, v.w);
    uint2 h;
    h.x = *(unsigned int*)&h0;
    h.y = *(unsigned int*)&h1;
    z16[(long)row * 64 + lane] = h;
    const float4 wv = ((const float4*)attn_w)[lane];
    float part = v.x * wv.x + v.y * wv.y + v.z * wv.z + v.w * wv.w;
    #pragma unroll
    for (int sh = 32; sh >= 1; sh >>= 1) part += __shfl_xor(part, sh);
    if (lane == 0) pvec[row] = __expf(part + attn_b[0]);
}

// Variant without the f16 copy (fallback when ws too small for z16).
__global__ __launch_bounds__(256)
void node_p_kernel(const float4* __restrict__ z4,
                   const float* __restrict__ attn_w,
                   const float* __restrict__ attn_b,
                   float* __restrict__ pvec, int N) {
    const int wave = threadIdx.x >> 6;
    const int lane = threadIdx.x & 63;
    const int row  = blockIdx.x * NWAVES + wave;
    if (row >= N) return;
    const float4 v  = z4[(long)row * 64 + lane];
    const float4 wv = ((const float4*)attn_w)[lane];
    float part = v.x * wv.x + v.y * wv.y + v.z * wv.z + v.w * wv.w;
    #pragma unroll
    for (int sh = 32; sh >= 1; sh >>= 1) part += __shfl_xor(part, sh);
    if (lane == 0) pvec[row] = __expf(part + attn_b[0]);
}

__device__ inline float4 h4_to_f4(uint2 h) {
    __half2 a = *(__half2*)&h.x;
    __half2 b = *(__half2*)&h.y;
    float2 fa = __half22float2(a);
    float2 fb = __half22float2(b);
    return make_float4(fa.x, fa.y, fb.x, fb.y);
}

// ---------- Kernel C: single-pass gather-accumulate from f16 z copy ----------
// One block per segment, 4 waves stride edges. den is lane-uniform per wave.
__global__ __launch_bounds__(256)
void segpool3_kernel(const uint2* __restrict__ z16,
                     const float* __restrict__ pvec,
                     const int* __restrict__ idx,
                     const int* __restrict__ offs,
                     float* __restrict__ out) {
    const int s     = blockIdx.x;
    const int start = offs[s];
    const int end   = offs[s + 1];
    const int tid   = threadIdx.x;
    if (end <= start) { out[(long)s * DDIM + tid] = 0.0f; return; }

    const int wave = tid >> 6;
    const int lane = tid & 63;

    float  den = 0.0f;
    float4 acc = make_float4(0.f, 0.f, 0.f, 0.f);

    int e = start + wave;
    // Unroll-by-8: batch the idx loads, then the dependent p/z loads.
    for (; e + 7 * NWAVES < end; e += 8 * NWAVES) {
        int rows[8];
        #pragma unroll
        for (int k = 0; k < 8; ++k) rows[k] = idx[e + k * NWAVES];
        float ps[8]; uint2 hs[8];
        #pragma unroll
        for (int k = 0; k < 8; ++k) {
            ps[k] = pvec[rows[k]];
            hs[k] = z16[(long)rows[k] * 64 + lane];
        }
        #pragma unroll
        for (int k = 0; k < 8; ++k) {
            const float4 v = h4_to_f4(hs[k]);
            den  += ps[k];
            acc.x += ps[k] * v.x;
            acc.y += ps[k] * v.y;
            acc.z += ps[k] * v.z;
            acc.w += ps[k] * v.w;
        }
    }
    for (; e < end; e += NWAVES) {
        const int row = idx[e];
        const float p = pvec[row];
        const float4 v = h4_to_f4(z16[(long)row * 64 + lane]);
        den  += p;
        acc.x += p * v.x;
        acc.y += p * v.y;
        acc.z += p * v.z;
        acc.w += p * v.w;
    }

    __shared__ float lds_den[NWAVES];
    __shared__ float lds_acc[NWAVES][DDIM];
    if (lane == 0) lds_den[wave] = den;   // lane-uniform within wave
    lds_acc[wave][4 * lane + 0] = acc.x;
    lds_acc[wave][4 * lane + 1] = acc.y;
    lds_acc[wave][4 * lane + 2] = acc.z;
    lds_acc[wave][4 * lane + 3] = acc.w;
    __syncthreads();

    const float D = lds_den[0] + lds_den[1] + lds_den[2] + lds_den[3];
    const float o = lds_acc[0][tid] + lds_acc[1][tid] +
                    lds_acc[2][tid] + lds_acc[3][tid];
    out[(long)s * DDIM + tid] = o / D;
}

// ---------- Kernel C': same single-pass structure, f32 z (no copy) ----------
__global__ __launch_bounds__(256)
void segpool3_f32_kernel(const float4* __restrict__ z4,
                         const float* __restrict__ pvec,
                         const int* __restrict__ idx,
                         const int* __restrict__ offs,
                         float* __restrict__ out) {
    const int s     = blockIdx.x;
    const int start = offs[s];
    const int end   = offs[s + 1];
    const int tid   = threadIdx.x;
    if (end <= start) { out[(long)s * DDIM + tid] = 0.0f; return; }
    const int wave = tid >> 6;
    const int lane = tid & 63;
    float  den = 0.0f;
    float4 acc = make_float4(0.f, 0.f, 0.f, 0.f);
    int e = start + wave;
    for (; e + 7 * NWAVES < end; e += 8 * NWAVES) {
        int rows[8];
        #pragma unroll
        for (int k = 0; k < 8; ++k) rows[k] = idx[e + k * NWAVES];
        float ps[8]; float4 vs[8];
        #pragma unroll
        for (int k = 0; k < 8; ++k) {
            ps[k] = pvec[rows[k]];
            vs[k] = z4[(long)rows[k] * 64 + lane];
        }
        #pragma unroll
        for (int k = 0; k < 8; ++k) {
            den  += ps[k];
            acc.x += ps[k] * vs[k].x;
            acc.y += ps[k] * vs[k].y;
            acc.z += ps[k] * vs[k].z;
            acc.w += ps[k] * vs[k].w;
        }
    }
    for (; e < end; e += NWAVES) {
        const int row = idx[e];
        const float p = pvec[row];
        const float4 v = z4[(long)row * 64 + lane];
        den  += p;
        acc.x += p * v.x;
        acc.y += p * v.y;
        acc.z += p * v.z;
        acc.w += p * v.w;
    }
    __shared__ float lds_den[NWAVES];
    __shared__ float lds_acc[NWAVES][DDIM];
    if (lane == 0) lds_den[wave] = den;
    lds_acc[wave][4 * lane + 0] = acc.x;
    lds_acc[wave][4 * lane + 1] = acc.y;
    lds_acc[wave][4 * lane + 2] = acc.z;
    lds_acc[wave][4 * lane + 3] = acc.w;
    __syncthreads();
    const float D = lds_den[0] + lds_den[1] + lds_den[2] + lds_den[3];
    const float o = lds_acc[0][tid] + lds_acc[1][tid] +
                    lds_acc[2][tid] + lds_acc[3][tid];
    out[(long)s * DDIM + tid] = o / D;
}

// ---------- Last-resort fallback: R1 fused online-softmax ----------
__global__ __launch_bounds__(256)
void segpool_fused_kernel(const float* __restrict__ z,
                          const float* __restrict__ attn_w,
                          const float* __restrict__ attn_b,
                          const int* __restrict__ idx,
                          const int* __restrict__ offs,
                          float* __restrict__ out) {
    const int s     = blockIdx.x;
    const int start = offs[s];
    const int end   = offs[s + 1];
    const int tid   = threadIdx.x;
    if (end <= start) { out[(long)s * DDIM + tid] = 0.0f; return; }
    const int wave = tid >> 6;
    const int lane = tid & 63;
    const float4 wv = ((const float4*)attn_w)[lane];
    const float  b  = attn_b[0];
    const float4* __restrict__ z4 = (const float4*)z;
    float  m = NEG_SENT, l = 0.0f;
    float4 acc = make_float4(0.f, 0.f, 0.f, 0.f);
    for (int e = start + wave; e < end; e += NWAVES) {
        const int   row = idx[e];
        const float4 v  = z4[(long)row * 64 + lane];
        float part = v.x * wv.x + v.y * wv.y + v.z * wv.z + v.w * wv.w;
        #pragma unroll
        for (int sh = 32; sh >= 1; sh >>= 1) part += __shfl_xor(part, sh);
        const float logit = part + b;
        const float nm    = fmaxf(m, logit);
        const float alpha = __expf(m - nm);
        const float p     = __expf(logit - nm);
        l = l * alpha + p;
        acc.x = acc.x * alpha + p * v.x;
        acc.y = acc.y * alpha + p * v.y;
        acc.z = acc.z * alpha + p * v.z;
        acc.w = acc.w * alpha + p * v.w;
        m = nm;
    }
    __shared__ float lds_m[NWAVES], lds_l[NWAVES];
    __shared__ float lds_acc[NWAVES][DDIM];
    if (lane == 0) { lds_m[wave] = m; lds_l[wave] = l; }
    __syncthreads();
    const float M = fmaxf(fmaxf(lds_m[0], lds_m[1]), fmaxf(lds_m[2], lds_m[3]));
    float den = 0.0f;
    #pragma unroll
    for (int w = 0; w < NWAVES; ++w) den += __expf(lds_m[w] - M) * lds_l[w];
    const float scale = __expf(m - M);
    lds_acc[wave][4 * lane + 0] = acc.x * scale;
    lds_acc[wave][4 * lane + 1] = acc.y * scale;
    lds_acc[wave][4 * lane + 2] = acc.z * scale;
    lds_acc[wave][4 * lane + 3] = acc.w * scale;
    __syncthreads();
    const float o = lds_acc[0][tid] + lds_acc[1][tid] +
                    lds_acc[2][tid] + lds_acc[3][tid];
    out[(long)s * DDIM + tid] = o / den;
}

extern "C" void kernel_launch(void* const* d_in, const int* in_sizes, int n_in,
                              void* d_out, int out_size, void* d_ws, size_t ws_size,
                              hipStream_t stream) {
    const float* z      = (const float*)d_in[0];
    const float* attn_w = (const float*)d_in[1];
    const float* attn_b = (const float*)d_in[2];
    const int*   idx    = (const int*)d_in[3];
    const int*   seg    = (const int*)d_in[4];
    float*       out    = (float*)d_out;

    const int E = in_sizes[3];
    const int S = out_size / DDIM;
    const int N = in_sizes[0] / DDIM;

    const int threads = 256;
    const int gridA = (S + 1 + threads - 1) / threads;
    const int gridN = (N + NWAVES - 1) / NWAVES;

    int* offs = (int*)d_ws;
    const size_t offs_bytes = (((size_t)(S + 1) * sizeof(int)) + 255) & ~(size_t)255;
    const size_t p_bytes    = (((size_t)N * sizeof(float)) + 255) & ~(size_t)255;
    const size_t z16_bytes  = (size_t)N * DDIM * sizeof(__half);
    const size_t need_full  = offs_bytes + p_bytes + z16_bytes;
    const size_t need_p     = offs_bytes + p_bytes;

    seg_offsets_kernel<<<gridA, threads, 0, stream>>>(seg, E, S, offs);

    if (ws_size >= need_full) {
        float* pvec = (float*)((char*)d_ws + offs_bytes);
        uint2* z16  = (uint2*)((char*)d_ws + offs_bytes + p_bytes);
        prep_kernel<<<gridN, threads, 0, stream>>>(
            (const float4*)z, attn_w, attn_b, z16, pvec, N);
        segpool3_kernel<<<S, threads, 0, stream>>>(
            (const uint2*)z16, pvec, idx, offs, out);
    } else if (ws_size >= need_p) {
        float* pvec = (float*)((char*)d_ws + offs_bytes);
        node_p_kernel<<<gridN, threads, 0, stream>>>(
            (const float4*)z, attn_w, attn_b, pvec, N);
        segpool3_f32_kernel<<<S, threads, 0, stream>>>(
            (const float4*)z, pvec, idx, offs, out);
    } else {
        segpool_fused_kernel<<<S, threads, 0, stream>>>(
            z, attn_w, attn_b, idx, offs, out);
    }
}